// Round 1
// baseline (1197.332 us; speedup 1.0000x reference)
//
#include <hip/hip_runtime.h>
#include <hip/hip_bf16.h>
#include <math.h>

// Problem constants
constexpr int cB = 4, cT = 256, cS = 400, cD = 512, cV = 50000, cNX = 50;
constexpr int cVEXT = cV + cNX;   // 50050

// ---------------------------------------------------------------------------
// Tiled fp32 GEMM:  C[i,j] = dot(A[i,:], W[j,:]) + bias[j]
// A: M x K row-major, W: N x K row-major (i.e. C = A * W^T), C: M x ldc
// BM=BN=64, BK=16, 256 threads, 4x4 accum per thread.
// ---------------------------------------------------------------------------
__global__ __launch_bounds__(256) void gemm_bt(
    const float* __restrict__ A, const float* __restrict__ W,
    const float* __restrict__ bias, float* __restrict__ C,
    int M, int N, int K, int ldc)
{
    __shared__ __align__(16) float As[16][68];
    __shared__ __align__(16) float Bs[16][68];

    const int tid = threadIdx.x;
    const int tx = tid & 15;        // 0..15 -> col group
    const int ty = tid >> 4;        // 0..15 -> row group
    const int bm = blockIdx.y * 64;
    const int bn = blockIdx.x * 64;

    const int lrow = tid >> 2;          // 0..63
    const int lk4  = (tid & 3) * 4;     // 0,4,8,12

    float acc[4][4] = {};

    for (int k0 = 0; k0 < K; k0 += 16) {
        // stage A tile (64 rows x 16 k), transposed into As[k][row]
        {
            int row = bm + lrow;
            float4 v = make_float4(0.f, 0.f, 0.f, 0.f);
            if (row < M) v = *(const float4*)(A + (size_t)row * K + k0 + lk4);
            As[lk4 + 0][lrow] = v.x; As[lk4 + 1][lrow] = v.y;
            As[lk4 + 2][lrow] = v.z; As[lk4 + 3][lrow] = v.w;
        }
        // stage W tile (64 cols x 16 k), transposed into Bs[k][col]
        {
            int col = bn + lrow;
            float4 v = make_float4(0.f, 0.f, 0.f, 0.f);
            if (col < N) v = *(const float4*)(W + (size_t)col * K + k0 + lk4);
            Bs[lk4 + 0][lrow] = v.x; Bs[lk4 + 1][lrow] = v.y;
            Bs[lk4 + 2][lrow] = v.z; Bs[lk4 + 3][lrow] = v.w;
        }
        __syncthreads();

        #pragma unroll
        for (int kk = 0; kk < 16; ++kk) {
            float4 av = *(const float4*)&As[kk][ty * 4];
            float4 bv = *(const float4*)&Bs[kk][tx * 4];
            float a_[4] = {av.x, av.y, av.z, av.w};
            float b_[4] = {bv.x, bv.y, bv.z, bv.w};
            #pragma unroll
            for (int i = 0; i < 4; ++i)
                #pragma unroll
                for (int j = 0; j < 4; ++j)
                    acc[i][j] += a_[i] * b_[j];
        }
        __syncthreads();
    }

    #pragma unroll
    for (int i = 0; i < 4; ++i) {
        int row = bm + ty * 4 + i;
        if (row >= M) continue;
        #pragma unroll
        for (int j = 0; j < 4; ++j) {
            int col = bn + tx * 4 + j;
            if (col < N) {
                float b = bias ? bias[col] : 0.f;
                C[(size_t)row * ldc + col] = acc[i][j] + b;
            }
        }
    }
}

// ---------------------------------------------------------------------------
// p_gen = sigmoid(x . pgen_w + pgen_b), one wave per row
// ---------------------------------------------------------------------------
__global__ __launch_bounds__(64) void pgen_kernel(
    const float* __restrict__ x, const float* __restrict__ w,
    const float* __restrict__ b, float* __restrict__ pgen)
{
    const int row = blockIdx.x;
    const int lane = threadIdx.x;
    const float* xr = x + (size_t)row * cD;
    float s = 0.f;
    for (int i = lane; i < cD; i += 64) s += xr[i] * w[i];
    #pragma unroll
    for (int off = 32; off; off >>= 1) s += __shfl_down(s, off);
    if (lane == 0) pgen[row] = 1.f / (1.f + __expf(-(s + b[0])));
}

// ---------------------------------------------------------------------------
// attention: per (b,t) row, scores over S, mask, softmax, scale by (1-pgen)
// ---------------------------------------------------------------------------
__global__ __launch_bounds__(256) void attn_kernel(
    const float* __restrict__ q, const float* __restrict__ k,
    const int* __restrict__ src_mask, const float* __restrict__ pgen,
    float* __restrict__ attn)
{
    constexpr float scale = 0.04419417382415922f;  // 1/sqrt(512)
    const int row = blockIdx.x;      // b*T + t
    const int b = row / cT;
    const int tid = threadIdx.x;

    __shared__ __align__(16) float qs[cD];
    __shared__ float sc[cS];
    __shared__ float red[4];

    for (int i = tid; i < cD; i += 256) qs[i] = q[(size_t)row * cD + i];
    __syncthreads();

    for (int s = tid; s < cS; s += 256) {
        const float* kr = k + ((size_t)b * cS + s) * cD;
        float dot = 0.f;
        #pragma unroll 4
        for (int i = 0; i < cD; i += 4) {
            float4 kv = *(const float4*)(kr + i);
            dot += qs[i] * kv.x + qs[i + 1] * kv.y + qs[i + 2] * kv.z + qs[i + 3] * kv.w;
        }
        float v = dot * scale;
        if (src_mask[b * cS + s] == 0) v = -1e9f;
        sc[s] = v;
    }
    __syncthreads();

    // block max
    float m = -3.4e38f;
    for (int s = tid; s < cS; s += 256) m = fmaxf(m, sc[s]);
    #pragma unroll
    for (int off = 32; off; off >>= 1) m = fmaxf(m, __shfl_down(m, off));
    if ((tid & 63) == 0) red[tid >> 6] = m;
    __syncthreads();
    m = fmaxf(fmaxf(red[0], red[1]), fmaxf(red[2], red[3]));
    __syncthreads();

    // exp + block sum
    float sum = 0.f;
    for (int s = tid; s < cS; s += 256) {
        float e = __expf(sc[s] - m);
        sc[s] = e;
        sum += e;
    }
    #pragma unroll
    for (int off = 32; off; off >>= 1) sum += __shfl_down(sum, off);
    if ((tid & 63) == 0) red[tid >> 6] = sum;
    __syncthreads();
    sum = red[0] + red[1] + red[2] + red[3];

    const float w = (1.f - pgen[row]) / sum;
    for (int s = tid; s < cS; s += 256)
        attn[(size_t)row * cS + s] = sc[s] * w;
}

// ---------------------------------------------------------------------------
// per-row max & exp-sum over V (logits live in d_out rows, stride VEXT)
// ---------------------------------------------------------------------------
__global__ __launch_bounds__(256) void rowstats_kernel(
    const float* __restrict__ out, float* __restrict__ rowmax,
    float* __restrict__ rowsum)
{
    const int row = blockIdx.x;
    const int tid = threadIdx.x;
    const float* lr = out + (size_t)row * cVEXT;
    __shared__ float red[4];

    float m = -3.4e38f;
    for (int v = tid; v < cV; v += 256) m = fmaxf(m, lr[v]);
    #pragma unroll
    for (int off = 32; off; off >>= 1) m = fmaxf(m, __shfl_down(m, off));
    if ((tid & 63) == 0) red[tid >> 6] = m;
    __syncthreads();
    m = fmaxf(fmaxf(red[0], red[1]), fmaxf(red[2], red[3]));
    __syncthreads();

    float s = 0.f;
    for (int v = tid; v < cV; v += 256) s += __expf(lr[v] - m);
    #pragma unroll
    for (int off = 32; off; off >>= 1) s += __shfl_down(s, off);
    if ((tid & 63) == 0) red[tid >> 6] = s;
    __syncthreads();
    if (tid == 0) {
        rowmax[row] = m;
        rowsum[row] = red[0] + red[1] + red[2] + red[3];
    }
}

// ---------------------------------------------------------------------------
// out[row, v<V] = pgen*softmax ; out[row, v>=V] = 0
// ---------------------------------------------------------------------------
__global__ __launch_bounds__(256) void transform_kernel(
    float* __restrict__ out, const float* __restrict__ pgen,
    const float* __restrict__ rowmax, const float* __restrict__ rowsum)
{
    const int row = blockIdx.y;
    const float inv = pgen[row] / rowsum[row];
    const float m = rowmax[row];
    const size_t base = (size_t)row * cVEXT;
    const int v0 = blockIdx.x * 1024 + threadIdx.x;
    #pragma unroll
    for (int j = 0; j < 4; ++j) {
        int v = v0 + j * 256;
        if (v < cVEXT) {
            float val = 0.f;
            if (v < cV) val = inv * __expf(out[base + v] - m);
            out[base + v] = val;
        }
    }
}

// ---------------------------------------------------------------------------
// scatter-add attn_dist into out at extended-vocab indices
// ---------------------------------------------------------------------------
__global__ __launch_bounds__(256) void scatter_kernel(
    float* __restrict__ out, const int* __restrict__ ebev,
    const float* __restrict__ attn)
{
    const int row = blockIdx.x;   // b*T + t
    const int b = row / cT;
    for (int s = threadIdx.x; s < cS; s += 256) {
        int v = ebev[b * cS + s];
        atomicAdd(out + (size_t)row * cVEXT + v, attn[(size_t)row * cS + s]);
    }
}

// ---------------------------------------------------------------------------
// final log(max(p, 1e-9))
// ---------------------------------------------------------------------------
__global__ __launch_bounds__(256) void log_kernel(float* __restrict__ out)
{
    const int row = blockIdx.y;
    const size_t base = (size_t)row * cVEXT;
    const int v0 = blockIdx.x * 1024 + threadIdx.x;
    #pragma unroll
    for (int j = 0; j < 4; ++j) {
        int v = v0 + j * 256;
        if (v < cVEXT)
            out[base + v] = __logf(fmaxf(out[base + v], 1e-9f));
    }
}

extern "C" void kernel_launch(void* const* d_in, const int* in_sizes, int n_in,
                              void* d_out, int out_size, void* d_ws, size_t ws_size,
                              hipStream_t stream)
{
    const float* x      = (const float*)d_in[0];   // (B,T,D)
    const float* enc    = (const float*)d_in[1];   // (B,S,D)
    const int*   mask   = (const int*)d_in[2];     // (B,1,S)
    const int*   ebev   = (const int*)d_in[3];     // (B,S)
    // d_in[4] extra_zeros unused (zeros)
    const float* fc_w   = (const float*)d_in[5];   // (V,D)
    const float* fc_b   = (const float*)d_in[6];   // (V,)
    const float* pgen_w = (const float*)d_in[7];   // (1,D)
    const float* pgen_b = (const float*)d_in[8];   // (1,)
    const float* wq     = (const float*)d_in[9];   // (D,D)
    const float* bq     = (const float*)d_in[10];  // (D,)
    const float* wk     = (const float*)d_in[11];  // (D,D)
    const float* bk     = (const float*)d_in[12];  // (D,)
    float* out = (float*)d_out;

    float* ws     = (float*)d_ws;
    float* q      = ws;                               // B*T*D
    float* kbuf   = q + (size_t)cB * cT * cD;         // B*S*D
    float* pgen   = kbuf + (size_t)cB * cS * cD;      // B*T
    float* attn   = pgen + cB * cT;                   // B*T*S
    float* rowmax = attn + (size_t)cB * cT * cS;      // B*T
    float* rowsum = rowmax + cB * cT;                 // B*T

    const dim3 blk(256);
    const int MQ = cB * cT;    // 1024
    const int MK = cB * cS;    // 1600

    // projections
    gemm_bt<<<dim3(cD / 64, MQ / 64), blk, 0, stream>>>(x, wq, bq, q, MQ, cD, cD, cD);
    gemm_bt<<<dim3(cD / 64, MK / 64), blk, 0, stream>>>(enc, wk, bk, kbuf, MK, cD, cD, cD);
    pgen_kernel<<<dim3(MQ), dim3(64), 0, stream>>>(x, pgen_w, pgen_b, pgen);

    // attention distribution (scaled by 1-pgen)
    attn_kernel<<<dim3(MQ), blk, 0, stream>>>(q, kbuf, mask, pgen, attn);

    // logits into d_out (stride VEXT)
    gemm_bt<<<dim3((cV + 63) / 64, MQ / 64), blk, 0, stream>>>(
        x, fc_w, fc_b, out, MQ, cV, cD, cVEXT);

    // vocab softmax stats
    rowstats_kernel<<<dim3(MQ), blk, 0, stream>>>(out, rowmax, rowsum);

    // p_gen * softmax, zero the NX tail
    transform_kernel<<<dim3((cVEXT + 1023) / 1024, MQ), blk, 0, stream>>>(
        out, pgen, rowmax, rowsum);

    // scatter attn_dist
    scatter_kernel<<<dim3(MQ), blk, 0, stream>>>(out, ebev, attn);

    // final log
    log_kernel<<<dim3((cVEXT + 1023) / 1024, MQ), blk, 0, stream>>>(out);
}

// Round 2
// 617.962 us; speedup vs baseline: 1.9375x; 1.9375x over previous
//
#include <hip/hip_runtime.h>
#include <hip/hip_bf16.h>
#include <math.h>

// Problem constants
constexpr int cB = 4, cT = 256, cS = 400, cD = 512, cV = 50000, cNX = 50;
constexpr int cVEXT = cV + cNX;   // 50050

typedef __attribute__((ext_vector_type(8))) short short8v;   // 8 bf16 = 4 VGPR
typedef __attribute__((ext_vector_type(4))) float floatx4;

// ---------------------------------------------------------------------------
// fp32 -> bf16 (RNE) cast, vectorized
// ---------------------------------------------------------------------------
__device__ inline ushort f2bf(float f) {
    union { float f; unsigned u; } v; v.f = f;
    unsigned r = (v.u + 0x7FFFu + ((v.u >> 16) & 1u)) >> 16;
    return (ushort)r;
}

__global__ __launch_bounds__(256) void cast_kernel(
    const float* __restrict__ src, ushort* __restrict__ dst, int n4)
{
    const int stride = gridDim.x * 256;
    for (int i = blockIdx.x * 256 + threadIdx.x; i < n4; i += stride) {
        float4 v = *(const float4*)(src + (size_t)i * 4);
        ushort4 o;
        o.x = f2bf(v.x); o.y = f2bf(v.y); o.z = f2bf(v.z); o.w = f2bf(v.w);
        *(ushort4*)(dst + (size_t)i * 4) = o;
    }
}

// ---------------------------------------------------------------------------
// bf16 MFMA GEMM: C[i,j] = dot(A[i,:], W[j,:]) + bias[j]   (fp32 out)
// A: M x K bf16 row-major, W: N x K bf16 row-major. 128x128 tile, BK=32,
// 256 threads = 4 waves (2x2), each wave 64x64 via 4x4 16x16x32 MFMAs.
// Requires M % 128 == 0, K % 32 == 0. N ragged: source rows clamped,
// epilogue masked.
// ---------------------------------------------------------------------------
__global__ __launch_bounds__(256) void gemm_mfma(
    const ushort* __restrict__ A, const ushort* __restrict__ W,
    const float* __restrict__ bias, float* __restrict__ C,
    int M, int N, int K, int ldc)
{
    __shared__ ushort As[128 * 32];
    __shared__ ushort Bs[128 * 32];

    const int tid  = threadIdx.x;
    const int lane = tid & 63;
    const int w    = tid >> 6;      // wave 0..3
    const int wm   = w >> 1;        // 0..1
    const int wn   = w & 1;         // 0..1
    const int bm   = blockIdx.y * 128;
    const int bn   = blockIdx.x * 128;

    // staging geometry: each wave's chunk = 16 rows x 32 k = 1 KB
    const int srow  = lane >> 2;         // 0..15
    const int skoff = (lane & 3) * 8;    // 0,8,16,24 (bf16 elems)

    floatx4 acc[4][4] = {};

    for (int k0 = 0; k0 < K; k0 += 32) {
        #pragma unroll
        for (int c = 0; c < 2; ++c) {
            const int lr = w * 32 + c * 16;
            const int grow = bm + lr + srow;
            const ushort* gp = A + (size_t)grow * K + k0 + skoff;
            __builtin_amdgcn_global_load_lds(
                (const __attribute__((address_space(1))) void*)gp,
                (__attribute__((address_space(3))) void*)&As[lr * 32], 16, 0, 0);
        }
        #pragma unroll
        for (int c = 0; c < 2; ++c) {
            const int lr = w * 32 + c * 16;
            int grow = bn + lr + srow;
            if (grow >= N) grow = N - 1;   // clamp; junk cols masked in epilogue
            const ushort* gp = W + (size_t)grow * K + k0 + skoff;
            __builtin_amdgcn_global_load_lds(
                (const __attribute__((address_space(1))) void*)gp,
                (__attribute__((address_space(3))) void*)&Bs[lr * 32], 16, 0, 0);
        }
        __syncthreads();   // drains vmcnt before LDS reads

        const int fr = lane & 15;
        const int fk = (lane >> 4) * 8;
        short8v a[4], b[4];
        #pragma unroll
        for (int mi = 0; mi < 4; ++mi)
            a[mi] = *(const short8v*)&As[(wm * 64 + mi * 16 + fr) * 32 + fk];
        #pragma unroll
        for (int ni = 0; ni < 4; ++ni)
            b[ni] = *(const short8v*)&Bs[(wn * 64 + ni * 16 + fr) * 32 + fk];

        #pragma unroll
        for (int mi = 0; mi < 4; ++mi)
            #pragma unroll
            for (int ni = 0; ni < 4; ++ni)
                acc[mi][ni] = __builtin_amdgcn_mfma_f32_16x16x32_bf16(
                    a[mi], b[ni], acc[mi][ni], 0, 0, 0);
        __syncthreads();
    }

    // epilogue: C/D layout col = lane&15, row = (lane>>4)*4 + reg
    const int cr = (lane >> 4) * 4;
    const int cc = lane & 15;
    #pragma unroll
    for (int mi = 0; mi < 4; ++mi) {
        const int rbase = bm + wm * 64 + mi * 16 + cr;
        #pragma unroll
        for (int ni = 0; ni < 4; ++ni) {
            const int col = bn + wn * 64 + ni * 16 + cc;
            if (col < N) {
                const float bv = bias ? bias[col] : 0.f;
                #pragma unroll
                for (int r = 0; r < 4; ++r)
                    C[(size_t)(rbase + r) * ldc + col] = acc[mi][ni][r] + bv;
            }
        }
    }
}

// ---------------------------------------------------------------------------
// Tiled fp32 GEMM (small projections):  C[i,j] = dot(A[i,:], W[j,:]) + bias[j]
// ---------------------------------------------------------------------------
__global__ __launch_bounds__(256) void gemm_bt(
    const float* __restrict__ A, const float* __restrict__ W,
    const float* __restrict__ bias, float* __restrict__ C,
    int M, int N, int K, int ldc)
{
    __shared__ __align__(16) float As[16][68];
    __shared__ __align__(16) float Bs[16][68];

    const int tid = threadIdx.x;
    const int tx = tid & 15;
    const int ty = tid >> 4;
    const int bm = blockIdx.y * 64;
    const int bn = blockIdx.x * 64;

    const int lrow = tid >> 2;
    const int lk4  = (tid & 3) * 4;

    float acc[4][4] = {};

    for (int k0 = 0; k0 < K; k0 += 16) {
        {
            int row = bm + lrow;
            float4 v = make_float4(0.f, 0.f, 0.f, 0.f);
            if (row < M) v = *(const float4*)(A + (size_t)row * K + k0 + lk4);
            As[lk4 + 0][lrow] = v.x; As[lk4 + 1][lrow] = v.y;
            As[lk4 + 2][lrow] = v.z; As[lk4 + 3][lrow] = v.w;
        }
        {
            int col = bn + lrow;
            float4 v = make_float4(0.f, 0.f, 0.f, 0.f);
            if (col < N) v = *(const float4*)(W + (size_t)col * K + k0 + lk4);
            Bs[lk4 + 0][lrow] = v.x; Bs[lk4 + 1][lrow] = v.y;
            Bs[lk4 + 2][lrow] = v.z; Bs[lk4 + 3][lrow] = v.w;
        }
        __syncthreads();

        #pragma unroll
        for (int kk = 0; kk < 16; ++kk) {
            float4 av = *(const float4*)&As[kk][ty * 4];
            float4 bv = *(const float4*)&Bs[kk][tx * 4];
            float a_[4] = {av.x, av.y, av.z, av.w};
            float b_[4] = {bv.x, bv.y, bv.z, bv.w};
            #pragma unroll
            for (int i = 0; i < 4; ++i)
                #pragma unroll
                for (int j = 0; j < 4; ++j)
                    acc[i][j] += a_[i] * b_[j];
        }
        __syncthreads();
    }

    #pragma unroll
    for (int i = 0; i < 4; ++i) {
        int row = bm + ty * 4 + i;
        if (row >= M) continue;
        #pragma unroll
        for (int j = 0; j < 4; ++j) {
            int col = bn + tx * 4 + j;
            if (col < N) {
                float b = bias ? bias[col] : 0.f;
                C[(size_t)row * ldc + col] = acc[i][j] + b;
            }
        }
    }
}

// ---------------------------------------------------------------------------
// p_gen = sigmoid(x . pgen_w + pgen_b), one wave per row
// ---------------------------------------------------------------------------
__global__ __launch_bounds__(64) void pgen_kernel(
    const float* __restrict__ x, const float* __restrict__ w,
    const float* __restrict__ b, float* __restrict__ pgen)
{
    const int row = blockIdx.x;
    const int lane = threadIdx.x;
    const float* xr = x + (size_t)row * cD;
    float s = 0.f;
    for (int i = lane; i < cD; i += 64) s += xr[i] * w[i];
    #pragma unroll
    for (int off = 32; off; off >>= 1) s += __shfl_down(s, off);
    if (lane == 0) pgen[row] = 1.f / (1.f + __expf(-(s + b[0])));
}

// ---------------------------------------------------------------------------
// attention: per (b,t) row, scores over S, mask, softmax, scale by (1-pgen)
// ---------------------------------------------------------------------------
__global__ __launch_bounds__(256) void attn_kernel(
    const float* __restrict__ q, const float* __restrict__ k,
    const int* __restrict__ src_mask, const float* __restrict__ pgen,
    float* __restrict__ attn)
{
    constexpr float scale = 0.04419417382415922f;  // 1/sqrt(512)
    const int row = blockIdx.x;      // b*T + t
    const int b = row / cT;
    const int tid = threadIdx.x;

    __shared__ __align__(16) float qs[cD];
    __shared__ float sc[cS];
    __shared__ float red[4];

    for (int i = tid; i < cD; i += 256) qs[i] = q[(size_t)row * cD + i];
    __syncthreads();

    for (int s = tid; s < cS; s += 256) {
        const float* kr = k + ((size_t)b * cS + s) * cD;
        float dot = 0.f;
        #pragma unroll 4
        for (int i = 0; i < cD; i += 4) {
            float4 kv = *(const float4*)(kr + i);
            dot += qs[i] * kv.x + qs[i + 1] * kv.y + qs[i + 2] * kv.z + qs[i + 3] * kv.w;
        }
        float v = dot * scale;
        if (src_mask[b * cS + s] == 0) v = -1e9f;
        sc[s] = v;
    }
    __syncthreads();

    float m = -3.4e38f;
    for (int s = tid; s < cS; s += 256) m = fmaxf(m, sc[s]);
    #pragma unroll
    for (int off = 32; off; off >>= 1) m = fmaxf(m, __shfl_down(m, off));
    if ((tid & 63) == 0) red[tid >> 6] = m;
    __syncthreads();
    m = fmaxf(fmaxf(red[0], red[1]), fmaxf(red[2], red[3]));
    __syncthreads();

    float sum = 0.f;
    for (int s = tid; s < cS; s += 256) {
        float e = __expf(sc[s] - m);
        sc[s] = e;
        sum += e;
    }
    #pragma unroll
    for (int off = 32; off; off >>= 1) sum += __shfl_down(sum, off);
    if ((tid & 63) == 0) red[tid >> 6] = sum;
    __syncthreads();
    sum = red[0] + red[1] + red[2] + red[3];

    const float w = (1.f - pgen[row]) / sum;
    for (int s = tid; s < cS; s += 256)
        attn[(size_t)row * cS + s] = sc[s] * w;
}

// ---------------------------------------------------------------------------
// per-row max & exp-sum over V
// ---------------------------------------------------------------------------
__global__ __launch_bounds__(256) void rowstats_kernel(
    const float* __restrict__ out, float* __restrict__ rowmax,
    float* __restrict__ rowsum)
{
    const int row = blockIdx.x;
    const int tid = threadIdx.x;
    const float* lr = out + (size_t)row * cVEXT;
    __shared__ float red[4];

    float m = -3.4e38f;
    for (int v = tid; v < cV; v += 256) m = fmaxf(m, lr[v]);
    #pragma unroll
    for (int off = 32; off; off >>= 1) m = fmaxf(m, __shfl_down(m, off));
    if ((tid & 63) == 0) red[tid >> 6] = m;
    __syncthreads();
    m = fmaxf(fmaxf(red[0], red[1]), fmaxf(red[2], red[3]));
    __syncthreads();

    float s = 0.f;
    for (int v = tid; v < cV; v += 256) s += __expf(lr[v] - m);
    #pragma unroll
    for (int off = 32; off; off >>= 1) s += __shfl_down(s, off);
    if ((tid & 63) == 0) red[tid >> 6] = s;
    __syncthreads();
    if (tid == 0) {
        rowmax[row] = m;
        rowsum[row] = red[0] + red[1] + red[2] + red[3];
    }
}

// ---------------------------------------------------------------------------
// out[row, v<V] = pgen*softmax ; out[row, v>=V] = 0
// ---------------------------------------------------------------------------
__global__ __launch_bounds__(256) void transform_kernel(
    float* __restrict__ out, const float* __restrict__ pgen,
    const float* __restrict__ rowmax, const float* __restrict__ rowsum)
{
    const int row = blockIdx.y;
    const float inv = pgen[row] / rowsum[row];
    const float m = rowmax[row];
    const size_t base = (size_t)row * cVEXT;
    const int v0 = blockIdx.x * 1024 + threadIdx.x;
    #pragma unroll
    for (int j = 0; j < 4; ++j) {
        int v = v0 + j * 256;
        if (v < cVEXT) {
            float val = 0.f;
            if (v < cV) val = inv * __expf(out[base + v] - m);
            out[base + v] = val;
        }
    }
}

// ---------------------------------------------------------------------------
// scatter-add attn_dist
// ---------------------------------------------------------------------------
__global__ __launch_bounds__(256) void scatter_kernel(
    float* __restrict__ out, const int* __restrict__ ebev,
    const float* __restrict__ attn)
{
    const int row = blockIdx.x;
    const int b = row / cT;
    for (int s = threadIdx.x; s < cS; s += 256) {
        int v = ebev[b * cS + s];
        atomicAdd(out + (size_t)row * cVEXT + v, attn[(size_t)row * cS + s]);
    }
}

// ---------------------------------------------------------------------------
// final log(max(p, 1e-9))
// ---------------------------------------------------------------------------
__global__ __launch_bounds__(256) void log_kernel(float* __restrict__ out)
{
    const int row = blockIdx.y;
    const size_t base = (size_t)row * cVEXT;
    const int v0 = blockIdx.x * 1024 + threadIdx.x;
    #pragma unroll
    for (int j = 0; j < 4; ++j) {
        int v = v0 + j * 256;
        if (v < cVEXT)
            out[base + v] = __logf(fmaxf(out[base + v], 1e-9f));
    }
}

extern "C" void kernel_launch(void* const* d_in, const int* in_sizes, int n_in,
                              void* d_out, int out_size, void* d_ws, size_t ws_size,
                              hipStream_t stream)
{
    const float* x      = (const float*)d_in[0];   // (B,T,D)
    const float* enc    = (const float*)d_in[1];   // (B,S,D)
    const int*   mask   = (const int*)d_in[2];     // (B,1,S)
    const int*   ebev   = (const int*)d_in[3];     // (B,S)
    const float* fc_w   = (const float*)d_in[5];   // (V,D)
    const float* fc_b   = (const float*)d_in[6];   // (V,)
    const float* pgen_w = (const float*)d_in[7];   // (1,D)
    const float* pgen_b = (const float*)d_in[8];   // (1,)
    const float* wq     = (const float*)d_in[9];   // (D,D)
    const float* bq     = (const float*)d_in[10];  // (D,)
    const float* wk     = (const float*)d_in[11];  // (D,D)
    const float* bk     = (const float*)d_in[12];  // (D,)
    float* out = (float*)d_out;

    float* ws     = (float*)d_ws;
    float* q      = ws;                               // B*T*D
    float* kbuf   = q + (size_t)cB * cT * cD;         // B*S*D
    float* pgen   = kbuf + (size_t)cB * cS * cD;      // B*T
    float* attn   = pgen + cB * cT;                   // B*T*S
    float* rowmax = attn + (size_t)cB * cT * cS;      // B*T
    float* rowsum = rowmax + cB * cT;                 // B*T
    ushort* xb    = (ushort*)(rowsum + cB * cT);      // B*T*D bf16
    ushort* wb    = xb + (size_t)cB * cT * cD;        // V*D bf16

    const dim3 blk(256);
    const int MQ = cB * cT;    // 1024
    const int MK = cB * cS;    // 1600

    // bf16 casts for the big GEMM
    cast_kernel<<<dim3(512), blk, 0, stream>>>(x, xb, (cB * cT * cD) / 4);
    cast_kernel<<<dim3(2048), blk, 0, stream>>>(fc_w, wb, (cV * cD) / 4);

    // projections (fp32)
    gemm_bt<<<dim3(cD / 64, MQ / 64), blk, 0, stream>>>(x, wq, bq, q, MQ, cD, cD, cD);
    gemm_bt<<<dim3(cD / 64, MK / 64), blk, 0, stream>>>(enc, wk, bk, kbuf, MK, cD, cD, cD);
    pgen_kernel<<<dim3(MQ), dim3(64), 0, stream>>>(x, pgen_w, pgen_b, pgen);

    // attention distribution (scaled by 1-pgen)
    attn_kernel<<<dim3(MQ), blk, 0, stream>>>(q, kbuf, mask, pgen, attn);

    // logits into d_out (stride VEXT) via bf16 MFMA
    gemm_mfma<<<dim3((cV + 127) / 128, MQ / 128), blk, 0, stream>>>(
        xb, wb, fc_b, out, MQ, cV, cD, cVEXT);

    // vocab softmax stats
    rowstats_kernel<<<dim3(MQ), blk, 0, stream>>>(out, rowmax, rowsum);

    // p_gen * softmax, zero the NX tail
    transform_kernel<<<dim3((cVEXT + 1023) / 1024, MQ), blk, 0, stream>>>(
        out, pgen, rowmax, rowsum);

    // scatter attn_dist
    scatter_kernel<<<dim3(MQ), blk, 0, stream>>>(out, ebev, attn);

    // final log
    log_kernel<<<dim3((cVEXT + 1023) / 1024, MQ), blk, 0, stream>>>(out);
}

// Round 3
// 536.528 us; speedup vs baseline: 2.2316x; 1.1518x over previous
//
#include <hip/hip_runtime.h>
#include <hip/hip_bf16.h>
#include <math.h>

// Problem constants
constexpr int cB = 4, cT = 256, cS = 400, cD = 512, cV = 50000, cNX = 50;
constexpr int cVEXT = cV + cNX;   // 50050
constexpr int cNBLK = (cV + 127) / 128;  // 391 col-blocks in the big GEMM

typedef __attribute__((ext_vector_type(8))) short short8v;   // 8 bf16 = 4 VGPR
typedef __attribute__((ext_vector_type(4))) float floatx4;

// ---------------------------------------------------------------------------
// fp32 -> bf16 (RNE) cast, vectorized
// ---------------------------------------------------------------------------
__device__ inline ushort f2bf(float f) {
    union { float f; unsigned u; } v; v.f = f;
    unsigned r = (v.u + 0x7FFFu + ((v.u >> 16) & 1u)) >> 16;
    return (ushort)r;
}

__global__ __launch_bounds__(256) void cast_kernel(
    const float* __restrict__ src, ushort* __restrict__ dst, int n4)
{
    const int stride = gridDim.x * 256;
    for (int i = blockIdx.x * 256 + threadIdx.x; i < n4; i += stride) {
        float4 v = *(const float4*)(src + (size_t)i * 4);
        ushort4 o;
        o.x = f2bf(v.x); o.y = f2bf(v.y); o.z = f2bf(v.z); o.w = f2bf(v.w);
        *(ushort4*)(dst + (size_t)i * 4) = o;
    }
}

// ---------------------------------------------------------------------------
// bf16 MFMA GEMM with fused per-block row softmax stats.
// C[i,j] = dot(A[i,:], W[j,:]) + bias[j]  (fp32 out, logits)
// Also writes, per (row, col-block): pm = max_j(logit), ps = sum_j exp(logit-pm)
// over this block's valid cols. 128x128 tile, BK=32, 4 waves (2x2).
// ---------------------------------------------------------------------------
__global__ __launch_bounds__(256) void gemm_mfma(
    const ushort* __restrict__ A, const ushort* __restrict__ W,
    const float* __restrict__ bias, float* __restrict__ C,
    float* __restrict__ pm, float* __restrict__ ps,
    int M, int N, int K, int ldc)
{
    __shared__ ushort As[128 * 32];
    __shared__ ushort Bs[128 * 32];
    __shared__ float sm_m[2][128];
    __shared__ float sm_s[2][128];

    const int tid  = threadIdx.x;
    const int lane = tid & 63;
    const int w    = tid >> 6;      // wave 0..3
    const int wm   = w >> 1;        // 0..1 row half
    const int wn   = w & 1;         // 0..1 col half
    const int bm   = blockIdx.y * 128;
    const int bn   = blockIdx.x * 128;

    const int srow  = lane >> 2;         // 0..15
    const int skoff = (lane & 3) * 8;    // bf16 elems

    floatx4 acc[4][4] = {};

    for (int k0 = 0; k0 < K; k0 += 32) {
        #pragma unroll
        for (int c = 0; c < 2; ++c) {
            const int lr = w * 32 + c * 16;
            const int grow = bm + lr + srow;
            const ushort* gp = A + (size_t)grow * K + k0 + skoff;
            __builtin_amdgcn_global_load_lds(
                (const __attribute__((address_space(1))) void*)gp,
                (__attribute__((address_space(3))) void*)&As[lr * 32], 16, 0, 0);
        }
        #pragma unroll
        for (int c = 0; c < 2; ++c) {
            const int lr = w * 32 + c * 16;
            int grow = bn + lr + srow;
            if (grow >= N) grow = N - 1;   // clamp; junk cols masked later
            const ushort* gp = W + (size_t)grow * K + k0 + skoff;
            __builtin_amdgcn_global_load_lds(
                (const __attribute__((address_space(1))) void*)gp,
                (__attribute__((address_space(3))) void*)&Bs[lr * 32], 16, 0, 0);
        }
        __syncthreads();

        const int fr = lane & 15;
        const int fk = (lane >> 4) * 8;
        short8v a[4], b[4];
        #pragma unroll
        for (int mi = 0; mi < 4; ++mi)
            a[mi] = *(const short8v*)&As[(wm * 64 + mi * 16 + fr) * 32 + fk];
        #pragma unroll
        for (int ni = 0; ni < 4; ++ni)
            b[ni] = *(const short8v*)&Bs[(wn * 64 + ni * 16 + fr) * 32 + fk];

        #pragma unroll
        for (int mi = 0; mi < 4; ++mi)
            #pragma unroll
            for (int ni = 0; ni < 4; ++ni)
                acc[mi][ni] = __builtin_amdgcn_mfma_f32_16x16x32_bf16(
                    a[mi], b[ni], acc[mi][ni], 0, 0, 0);
        __syncthreads();
    }

    // ---- epilogue: bias, per-row block stats, store ----
    const int g  = lane >> 4;       // 0..3
    const int cc = lane & 15;

    float bv[4];
    bool valid[4];
    #pragma unroll
    for (int ni = 0; ni < 4; ++ni) {
        const int col = bn + wn * 64 + ni * 16 + cc;
        valid[ni] = (col < N);
        bv[ni] = valid[ni] ? bias[col] : 0.f;
    }
    #pragma unroll
    for (int mi = 0; mi < 4; ++mi)
        #pragma unroll
        for (int ni = 0; ni < 4; ++ni)
            #pragma unroll
            for (int r = 0; r < 4; ++r)
                acc[mi][ni][r] += bv[ni];

    // per-(mi,r) row stats over this wave's 64 cols
    #pragma unroll
    for (int mi = 0; mi < 4; ++mi) {
        #pragma unroll
        for (int r = 0; r < 4; ++r) {
            float mx = -INFINITY;
            #pragma unroll
            for (int ni = 0; ni < 4; ++ni)
                if (valid[ni]) mx = fmaxf(mx, acc[mi][ni][r]);
            #pragma unroll
            for (int sw = 1; sw < 16; sw <<= 1)
                mx = fmaxf(mx, __shfl_xor(mx, sw));
            float sm = 0.f;
            #pragma unroll
            for (int ni = 0; ni < 4; ++ni)
                if (valid[ni]) sm += __expf(acc[mi][ni][r] - mx);
            #pragma unroll
            for (int sw = 1; sw < 16; sw <<= 1)
                sm += __shfl_xor(sm, sw);
            if (cc == 0) {
                const int lr = wm * 64 + mi * 16 + g * 4 + r;
                sm_m[wn][lr] = mx;
                sm_s[wn][lr] = sm;
            }
        }
    }
    __syncthreads();
    if (tid < 128) {
        const float m0 = sm_m[0][tid], m1 = sm_m[1][tid];
        const float s0 = sm_s[0][tid], s1 = sm_s[1][tid];
        const float mm = fmaxf(m0, m1);
        const float ss = s0 * __expf(m0 - mm) + s1 * __expf(m1 - mm);
        const int grow = bm + tid;
        pm[(size_t)grow * cNBLK + blockIdx.x] = mm;
        ps[(size_t)grow * cNBLK + blockIdx.x] = ss;
    }

    // store logits
    const int cr = g * 4;
    #pragma unroll
    for (int mi = 0; mi < 4; ++mi) {
        const int rbase = bm + wm * 64 + mi * 16 + cr;
        #pragma unroll
        for (int ni = 0; ni < 4; ++ni) {
            const int col = bn + wn * 64 + ni * 16 + cc;
            if (valid[ni]) {
                #pragma unroll
                for (int r = 0; r < 4; ++r)
                    C[(size_t)(rbase + r) * ldc + col] = acc[mi][ni][r];
            }
        }
    }
}

// ---------------------------------------------------------------------------
// combine partial (m,s) -> rowmax, rowsum. One block per row.
// ---------------------------------------------------------------------------
__global__ __launch_bounds__(256) void combine_kernel(
    const float* __restrict__ pm, const float* __restrict__ ps,
    float* __restrict__ rowmax, float* __restrict__ rowsum)
{
    const int row = blockIdx.x;
    const int tid = threadIdx.x;
    float m = -INFINITY, s = 0.f;
    for (int i = tid; i < cNBLK; i += 256) {
        const float mi = pm[(size_t)row * cNBLK + i];
        const float si = ps[(size_t)row * cNBLK + i];
        const float nm = fmaxf(m, mi);
        s = s * __expf(m - nm) + si * __expf(mi - nm);
        m = nm;
    }
    #pragma unroll
    for (int sw = 1; sw < 64; sw <<= 1) {
        const float mo = __shfl_xor(m, sw);
        const float so = __shfl_xor(s, sw);
        const float nm = fmaxf(m, mo);
        s = s * __expf(m - nm) + so * __expf(mo - nm);
        m = nm;
    }
    __shared__ float rm[4], rs[4];
    if ((tid & 63) == 0) { rm[tid >> 6] = m; rs[tid >> 6] = s; }
    __syncthreads();
    if (tid == 0) {
        m = rm[0]; s = rs[0];
        #pragma unroll
        for (int i = 1; i < 4; ++i) {
            const float nm = fmaxf(m, rm[i]);
            s = s * __expf(m - nm) + rs[i] * __expf(rm[i] - nm);
            m = nm;
        }
        rowmax[row] = m;
        rowsum[row] = s;
    }
}

// ---------------------------------------------------------------------------
// fused transform + log: out = log(max(pgen*exp(logit-m)/sum, 1e-9)),
// tail (v>=V) = log(1e-9). float2 (rows are 8B-aligned).
// ---------------------------------------------------------------------------
__global__ __launch_bounds__(256) void transform_log_kernel(
    float* __restrict__ out, const float* __restrict__ pgen,
    const float* __restrict__ rowmax, const float* __restrict__ rowsum)
{
    const int row = blockIdx.y;
    const float inv = pgen[row] / rowsum[row];
    const float m = rowmax[row];
    constexpr float LOGMIN = -20.72326583694641f;   // log(1e-9)
    constexpr int NF2 = cVEXT / 2;    // 25025
    constexpr int NF2V = cV / 2;      // 25000 (V even -> clean split)
    float2* rp = (float2*)(out + (size_t)row * cVEXT);
    for (int i = blockIdx.x * 256 + threadIdx.x; i < NF2; i += gridDim.x * 256) {
        float2 v = rp[i];
        float2 o;
        if (i < NF2V) {
            o.x = __logf(fmaxf(inv * __expf(v.x - m), 1e-9f));
            o.y = __logf(fmaxf(inv * __expf(v.y - m), 1e-9f));
        } else {
            o.x = LOGMIN; o.y = LOGMIN;
        }
        rp[i] = o;
    }
}

// ---------------------------------------------------------------------------
// scatter fixup in log space: out[row,p] = log(exp(out[row,p]) + sum_adds(p))
// one block per row; duplicates resolved via leader scan in LDS.
// ---------------------------------------------------------------------------
__global__ __launch_bounds__(256) void fixup_kernel(
    float* __restrict__ out, const int* __restrict__ ebev,
    const float* __restrict__ attn)
{
    const int row = blockIdx.x;
    const int b = row / cT;
    __shared__ int pos[cS];
    __shared__ float add[cS];
    for (int s = threadIdx.x; s < cS; s += 256) {
        pos[s] = ebev[b * cS + s];
        add[s] = attn[(size_t)row * cS + s];
    }
    __syncthreads();
    for (int s = threadIdx.x; s < cS; s += 256) {
        const int p = pos[s];
        bool leader = true;
        for (int s2 = 0; s2 < s; ++s2)
            if (pos[s2] == p) { leader = false; break; }
        if (!leader) continue;
        float sum = add[s];
        for (int s2 = s + 1; s2 < cS; ++s2)
            if (pos[s2] == p) sum += add[s2];
        const size_t off = (size_t)row * cVEXT + p;
        out[off] = __logf(__expf(out[off]) + sum);
    }
}

// ---------------------------------------------------------------------------
// Tiled fp32 GEMM (small projections)
// ---------------------------------------------------------------------------
__global__ __launch_bounds__(256) void gemm_bt(
    const float* __restrict__ A, const float* __restrict__ W,
    const float* __restrict__ bias, float* __restrict__ C,
    int M, int N, int K, int ldc)
{
    __shared__ __align__(16) float As[16][68];
    __shared__ __align__(16) float Bs[16][68];

    const int tid = threadIdx.x;
    const int tx = tid & 15;
    const int ty = tid >> 4;
    const int bm = blockIdx.y * 64;
    const int bn = blockIdx.x * 64;

    const int lrow = tid >> 2;
    const int lk4  = (tid & 3) * 4;

    float acc[4][4] = {};

    for (int k0 = 0; k0 < K; k0 += 16) {
        {
            int row = bm + lrow;
            float4 v = make_float4(0.f, 0.f, 0.f, 0.f);
            if (row < M) v = *(const float4*)(A + (size_t)row * K + k0 + lk4);
            As[lk4 + 0][lrow] = v.x; As[lk4 + 1][lrow] = v.y;
            As[lk4 + 2][lrow] = v.z; As[lk4 + 3][lrow] = v.w;
        }
        {
            int col = bn + lrow;
            float4 v = make_float4(0.f, 0.f, 0.f, 0.f);
            if (col < N) v = *(const float4*)(W + (size_t)col * K + k0 + lk4);
            Bs[lk4 + 0][lrow] = v.x; Bs[lk4 + 1][lrow] = v.y;
            Bs[lk4 + 2][lrow] = v.z; Bs[lk4 + 3][lrow] = v.w;
        }
        __syncthreads();

        #pragma unroll
        for (int kk = 0; kk < 16; ++kk) {
            float4 av = *(const float4*)&As[kk][ty * 4];
            float4 bv = *(const float4*)&Bs[kk][tx * 4];
            float a_[4] = {av.x, av.y, av.z, av.w};
            float b_[4] = {bv.x, bv.y, bv.z, bv.w};
            #pragma unroll
            for (int i = 0; i < 4; ++i)
                #pragma unroll
                for (int j = 0; j < 4; ++j)
                    acc[i][j] += a_[i] * b_[j];
        }
        __syncthreads();
    }

    #pragma unroll
    for (int i = 0; i < 4; ++i) {
        int row = bm + ty * 4 + i;
        if (row >= M) continue;
        #pragma unroll
        for (int j = 0; j < 4; ++j) {
            int col = bn + tx * 4 + j;
            if (col < N) {
                float b = bias ? bias[col] : 0.f;
                C[(size_t)row * ldc + col] = acc[i][j] + b;
            }
        }
    }
}

// ---------------------------------------------------------------------------
// p_gen = sigmoid(x . pgen_w + pgen_b)
// ---------------------------------------------------------------------------
__global__ __launch_bounds__(64) void pgen_kernel(
    const float* __restrict__ x, const float* __restrict__ w,
    const float* __restrict__ b, float* __restrict__ pgen)
{
    const int row = blockIdx.x;
    const int lane = threadIdx.x;
    const float* xr = x + (size_t)row * cD;
    float s = 0.f;
    for (int i = lane; i < cD; i += 64) s += xr[i] * w[i];
    #pragma unroll
    for (int off = 32; off; off >>= 1) s += __shfl_down(s, off);
    if (lane == 0) pgen[row] = 1.f / (1.f + __expf(-(s + b[0])));
}

// ---------------------------------------------------------------------------
// attention distribution (scaled by 1-pgen)
// ---------------------------------------------------------------------------
__global__ __launch_bounds__(256) void attn_kernel(
    const float* __restrict__ q, const float* __restrict__ k,
    const int* __restrict__ src_mask, const float* __restrict__ pgen,
    float* __restrict__ attn)
{
    constexpr float scale = 0.04419417382415922f;  // 1/sqrt(512)
    const int row = blockIdx.x;      // b*T + t
    const int b = row / cT;
    const int tid = threadIdx.x;

    __shared__ __align__(16) float qs[cD];
    __shared__ float sc[cS];
    __shared__ float red[4];

    for (int i = tid; i < cD; i += 256) qs[i] = q[(size_t)row * cD + i];
    __syncthreads();

    for (int s = tid; s < cS; s += 256) {
        const float* kr = k + ((size_t)b * cS + s) * cD;
        float dot = 0.f;
        #pragma unroll 4
        for (int i = 0; i < cD; i += 4) {
            float4 kv = *(const float4*)(kr + i);
            dot += qs[i] * kv.x + qs[i + 1] * kv.y + qs[i + 2] * kv.z + qs[i + 3] * kv.w;
        }
        float v = dot * scale;
        if (src_mask[b * cS + s] == 0) v = -1e9f;
        sc[s] = v;
    }
    __syncthreads();

    float m = -3.4e38f;
    for (int s = tid; s < cS; s += 256) m = fmaxf(m, sc[s]);
    #pragma unroll
    for (int off = 32; off; off >>= 1) m = fmaxf(m, __shfl_down(m, off));
    if ((tid & 63) == 0) red[tid >> 6] = m;
    __syncthreads();
    m = fmaxf(fmaxf(red[0], red[1]), fmaxf(red[2], red[3]));
    __syncthreads();

    float sum = 0.f;
    for (int s = tid; s < cS; s += 256) {
        float e = __expf(sc[s] - m);
        sc[s] = e;
        sum += e;
    }
    #pragma unroll
    for (int off = 32; off; off >>= 1) sum += __shfl_down(sum, off);
    if ((tid & 63) == 0) red[tid >> 6] = sum;
    __syncthreads();
    sum = red[0] + red[1] + red[2] + red[3];

    const float w = (1.f - pgen[row]) / sum;
    for (int s = tid; s < cS; s += 256)
        attn[(size_t)row * cS + s] = sc[s] * w;
}

extern "C" void kernel_launch(void* const* d_in, const int* in_sizes, int n_in,
                              void* d_out, int out_size, void* d_ws, size_t ws_size,
                              hipStream_t stream)
{
    const float* x      = (const float*)d_in[0];   // (B,T,D)
    const float* enc    = (const float*)d_in[1];   // (B,S,D)
    const int*   mask   = (const int*)d_in[2];     // (B,1,S)
    const int*   ebev   = (const int*)d_in[3];     // (B,S)
    const float* fc_w   = (const float*)d_in[5];   // (V,D)
    const float* fc_b   = (const float*)d_in[6];   // (V,)
    const float* pgen_w = (const float*)d_in[7];   // (1,D)
    const float* pgen_b = (const float*)d_in[8];   // (1,)
    const float* wq     = (const float*)d_in[9];   // (D,D)
    const float* bq     = (const float*)d_in[10];  // (D,)
    const float* wk     = (const float*)d_in[11];  // (D,D)
    const float* bk     = (const float*)d_in[12];  // (D,)
    float* out = (float*)d_out;

    float* ws     = (float*)d_ws;
    float* q      = ws;                               // B*T*D
    float* kbuf   = q + (size_t)cB * cT * cD;         // B*S*D
    float* pgen   = kbuf + (size_t)cB * cS * cD;      // B*T
    float* attn   = pgen + cB * cT;                   // B*T*S
    float* rowmax = attn + (size_t)cB * cT * cS;      // B*T
    float* rowsum = rowmax + cB * cT;                 // B*T
    float* pm     = rowsum + cB * cT;                 // B*T*NBLK
    float* ps     = pm + (size_t)cB * cT * cNBLK;     // B*T*NBLK
    ushort* xb    = (ushort*)(ps + (size_t)cB * cT * cNBLK);  // B*T*D bf16
    ushort* wb    = xb + (size_t)cB * cT * cD;        // V*D bf16

    const dim3 blk(256);
    const int MQ = cB * cT;    // 1024
    const int MK = cB * cS;    // 1600

    // bf16 casts for the big GEMM
    cast_kernel<<<dim3(512), blk, 0, stream>>>(x, xb, (cB * cT * cD) / 4);
    cast_kernel<<<dim3(2048), blk, 0, stream>>>(fc_w, wb, (cV * cD) / 4);

    // projections (fp32)
    gemm_bt<<<dim3(cD / 64, MQ / 64), blk, 0, stream>>>(x, wq, bq, q, MQ, cD, cD, cD);
    gemm_bt<<<dim3(cD / 64, MK / 64), blk, 0, stream>>>(enc, wk, bk, kbuf, MK, cD, cD, cD);
    pgen_kernel<<<dim3(MQ), dim3(64), 0, stream>>>(x, pgen_w, pgen_b, pgen);

    // attention distribution
    attn_kernel<<<dim3(MQ), blk, 0, stream>>>(q, kbuf, mask, pgen, attn);

    // logits + fused row stats partials
    gemm_mfma<<<dim3(cNBLK, MQ / 128), blk, 0, stream>>>(
        xb, wb, fc_b, out, pm, ps, MQ, cV, cD, cVEXT);

    // combine partials -> rowmax, rowsum
    combine_kernel<<<dim3(MQ), blk, 0, stream>>>(pm, ps, rowmax, rowsum);

    // fused p_gen*softmax + log (tail = log(1e-9))
    transform_log_kernel<<<dim3(25, MQ), blk, 0, stream>>>(out, pgen, rowmax, rowsum);

    // scatter fixup in log space
    fixup_kernel<<<dim3(MQ), blk, 0, stream>>>(out, ebev, attn);
}